// Round 1
// baseline (333.070 us; speedup 1.0000x reference)
//
#include <hip/hip_runtime.h>
#include <hip/hip_bf16.h>
#include <hip/hip_cooperative_groups.h>

#define NN 12288
#define ED 256
#define ES 32
#define NPC (NN - 1)      // parent->child edges (edges rows NN..2NN-2)
#define GRID 512
#define BLK 256
#define W1T_LD 264        // padded leading dim (bf16 elems) -> bank-balanced ds_read_b128

typedef __hip_bfloat16 bf16;
typedef __attribute__((ext_vector_type(8))) short s8v;            // 8 x bf16 (4 VGPR)
typedef __attribute__((ext_vector_type(8))) unsigned short u8v;
typedef __attribute__((ext_vector_type(4))) float f4v;

namespace cg = cooperative_groups;

// ---- dtype detect: f32 tensors reinterpreted as bf16 contain mantissa words
// with random exponents -> huge magnitudes. Deterministic per wave (all waves
// scan the same first 512 bf16-words), so no global flag is needed.
__device__ __forceinline__ bool detect_f32(const void* W1) {
    const unsigned short* p = (const unsigned short*)W1 + (threadIdx.x & 63) * 8;
    u8v v = *(const u8v*)p;
    int huge = 0;
#pragma unroll
    for (int i = 0; i < 8; ++i) {
        unsigned short m = (unsigned short)(v[i] & 0x7fff);
        huge |= (m >= 0x4620);   // |bf16| >= 10240.0
    }
    return __any(huge) != 0;
}

// ---- LDS staging: W2 as f32 [32][33] (conflict-free j-reads), b1|b2 as f32[64]
__device__ __forceinline__ void stage_w2b(bool f32, const void* W2, const void* b1,
                                          const void* b2, float* sW2, float* sB) {
    int t = threadIdx.x;
    for (int i = t; i < ES * ES; i += BLK) {
        float v = f32 ? ((const float*)W2)[i] : __bfloat162float(((const bf16*)W2)[i]);
        sW2[(i >> 5) * 33 + (i & 31)] = v;
    }
    if (t < ES)          sB[t] = f32 ? ((const float*)b1)[t]      : __bfloat162float(((const bf16*)b1)[t]);
    else if (t < 2 * ES) sB[t] = f32 ? ((const float*)b2)[t - ES] : __bfloat162float(((const bf16*)b2)[t - ES]);
}

// ---- W1^T staged in LDS as bf16 [32 cols][W1T_LD k] (bf16 path only).
// thread t owns W1 row t (32 bf16, 4x16B loads), scatters to column-major.
__device__ __forceinline__ void stage_w1t(const void* W1, unsigned short* sW1T) {
    int k = threadIdx.x;
    const u8v* src = (const u8v*)((const unsigned short*)W1 + (size_t)k * ES);
#pragma unroll
    for (int g = 0; g < 4; ++g) {
        u8v v = src[g];
#pragma unroll
        for (int e = 0; e < 8; ++e)
            sW1T[(g * 8 + e) * W1T_LD + k] = v[e];
    }
}

// ---- phase: zero deg + acc1 + acc2 (contiguous prefix of ws)
__device__ __forceinline__ void phase_zero(unsigned tid, unsigned stride, float4* z) {
    const unsigned n4 = (NN * 4 + 2u * NN * ES * 4) / 16;
    for (unsigned i = tid; i < n4; i += stride) z[i] = make_float4(0.f, 0.f, 0.f, 0.f);
}

// ---- phase: deg = child-count (pc edges only; consumers use deg+1)
__device__ __forceinline__ void phase_deg(unsigned tid, unsigned stride,
                                          const int* edges, unsigned* deg) {
    for (unsigned t = tid; t < NPC; t += stride)
        atomicAdd(&deg[edges[2 * (NN + t)]], 1u);
}

// ---- phase: X1 = emb@W1 + b1 via MFMA (bf16). One 16-node x 32-col tile/wave.
// m97 pattern: A row-major [16][K], B^T row-major [32][K], lane q=row/col,
// k-offset hi*8; C/D mapping col=lane&15, row=(lane>>4)*4+i  [m89-verified].
__device__ __forceinline__ void phase_x1_mfma(int gw, const int* node_ids, const void* table,
                                              const unsigned short* sW1T, const float* sB, float* X) {
    if (gw >= NN / 16) return;
    int lane = threadIdx.x & 63;
    int q = lane & 15, hi = lane >> 4;
    int n0 = gw * 16;
    size_t id = (size_t)node_ids[n0 + q];
    const short* ap = (const short*)table + id * ED + hi * 8;
    const unsigned short* bp0 = sW1T + q * W1T_LD + hi * 8;
    const unsigned short* bp1 = sW1T + (q + 16) * W1T_LD + hi * 8;
    f4v a0 = {0.f, 0.f, 0.f, 0.f}, a1 = {0.f, 0.f, 0.f, 0.f};
#pragma unroll
    for (int s = 0; s < ED / 32; ++s) {
        s8v a   = *(const s8v*)(ap + s * 32);
        s8v b0  = *(const s8v*)(bp0 + s * 32);
        s8v b1v = *(const s8v*)(bp1 + s * 32);
        a0 = __builtin_amdgcn_mfma_f32_16x16x32_bf16(a, b0,  a0, 0, 0, 0);
        a1 = __builtin_amdgcn_mfma_f32_16x16x32_bf16(a, b1v, a1, 0, 0, 0);
    }
    float bv0 = sB[q], bv1 = sB[q + 16];
#pragma unroll
    for (int i = 0; i < 4; ++i) {
        int n = n0 + hi * 4 + i;
        X[n * ES + q]      = a0[i] + bv0;
        X[n * ES + q + 16] = a1[i] + bv1;
    }
}

// ---- phase: X1 scalar f32 fallback (correctness path; inputs are bf16 in practice)
__device__ __forceinline__ void phase_x1_f32(unsigned tid, unsigned stride, const int* node_ids,
                                             const void* table, const void* W1,
                                             const float* sB, float* X) {
    for (unsigned t = tid; t < NN * ES; t += stride) {
        int n = t >> 5, j = t & 31;
        const float* e = (const float*)table + (size_t)node_ids[n] * ED;
        const float* w = (const float*)W1;
        float acc = sB[j];
#pragma unroll 8
        for (int k = 0; k < ED; ++k) acc += e[k] * w[k * ES + j];
        X[t] = acc;
    }
}

// ---- phase: acc1[r] += w_rc * X1[c] over pc edges only (self folded at use)
__device__ __forceinline__ void phase_scatter1(unsigned tid, unsigned stride, const int* edges,
                                               const unsigned* deg, const float* X, float* acc1) {
    for (unsigned t = tid; t < NPC * ES; t += stride) {
        int e = t >> 5, k = t & 31;
        int r = edges[2 * (NN + e)], c = edges[2 * (NN + e) + 1];
        float w = rsqrtf((float)deg[r] + 1.f) * rsqrtf((float)deg[c] + 1.f);
        atomicAdd(&acc1[r * ES + k], w * X[c * ES + k]);
    }
}

// ---- phase: per pc edge, recompute X2[c] on the fly (shfl mat-vec vs LDS W2),
// scatter w_rc * X2[c] into acc2[r]. h1[c] = relu(acc1[c] + (1/deg_c) X1[c]).
__device__ __forceinline__ void phase_x2scatter(unsigned tid, unsigned stride, const int* edges,
                                                const unsigned* deg, const float* acc1, const float* X,
                                                const float* sW2, const float* sB, float* acc2) {
    for (unsigned t = tid; t < NPC * ES; t += stride) {
        int e = t >> 5, j = t & 31;
        int r = edges[2 * (NN + e)], c = edges[2 * (NN + e) + 1];
        float rc = rsqrtf((float)deg[c] + 1.f);
        float h = fmaxf(acc1[c * ES + j] + (rc * rc) * X[c * ES + j], 0.f);
        float x2 = sB[ES + j];
#pragma unroll
        for (int k = 0; k < ES; ++k)
            x2 += __shfl(h, k, ES) * sW2[k * 33 + j];
        float w = rsqrtf((float)deg[r] + 1.f) * rc;
        atomicAdd(&acc2[r * ES + j], w * x2);
    }
}

// ---- phase: out[n] = relu(acc2[n] + (1/deg_n) * X2[n]), X2[n] recomputed
__device__ __forceinline__ void phase_out(unsigned tid, unsigned stride, bool f32,
                                          const unsigned* deg, const float* acc1, const float* X,
                                          const float* sW2, const float* sB, const float* acc2,
                                          void* out) {
    for (unsigned t = tid; t < NN * ES; t += stride) {
        int n = t >> 5, j = t & 31;
        float rn = rsqrtf((float)deg[n] + 1.f);
        float sw = rn * rn;
        float h = fmaxf(acc1[n * ES + j] + sw * X[n * ES + j], 0.f);
        float x2 = sB[ES + j];
#pragma unroll
        for (int k = 0; k < ES; ++k)
            x2 += __shfl(h, k, ES) * sW2[k * 33 + j];
        float v = fmaxf(acc2[n * ES + j] + sw * x2, 0.f);
        if (f32) ((float*)out)[t] = v;
        else     ((bf16*)out)[t]  = __float2bfloat16(v);
    }
}

// =========================== cooperative mono-kernel ===========================
__global__ __launch_bounds__(BLK, 2)
void k_mono(const int* node_ids, const int* edges, const void* table, const void* W1,
            const void* b1, const void* W2, const void* b2, void* out,
            unsigned* deg, float* acc1, float* acc2, float* X) {
    __shared__ unsigned short sW1T[ES * W1T_LD];
    __shared__ float sW2[ES * 33];
    __shared__ float sB[2 * ES];
    cg::grid_group g = cg::this_grid();
    unsigned tid = blockIdx.x * BLK + threadIdx.x;
    unsigned stride = gridDim.x * BLK;

    bool f32 = detect_f32(W1);
    stage_w2b(f32, W2, b1, b2, sW2, sB);
    if (!f32 && (int)blockIdx.x < (NN / 16 + 3) / 4) stage_w1t(W1, sW1T);
    phase_zero(tid, stride, (float4*)deg);          // deg | acc1 | acc2 contiguous
    g.sync();

    phase_deg(tid, stride, edges, deg);
    if (!f32) phase_x1_mfma((int)blockIdx.x * 4 + (int)(threadIdx.x >> 6), node_ids, table, sW1T, sB, X);
    else      phase_x1_f32(tid, stride, node_ids, table, W1, sB, X);
    g.sync();

    phase_scatter1(tid, stride, edges, deg, X, acc1);
    g.sync();

    phase_x2scatter(tid, stride, edges, deg, acc1, X, sW2, sB, acc2);
    g.sync();

    phase_out(tid, stride, f32, deg, acc1, X, sW2, sB, acc2, out);
}

// ====================== non-cooperative fallback kernels ======================
__global__ __launch_bounds__(BLK, 2)
void k_f1(const int* node_ids, const int* edges, const void* table, const void* W1,
          const void* b1, const void* W2, const void* b2, unsigned* deg, float* X) {
    __shared__ unsigned short sW1T[ES * W1T_LD];
    __shared__ float sW2[ES * 33];
    __shared__ float sB[2 * ES];
    bool f32 = detect_f32(W1);
    stage_w2b(f32, W2, b1, b2, sW2, sB);
    if (!f32) stage_w1t(W1, sW1T);
    __syncthreads();
    unsigned tid = blockIdx.x * BLK + threadIdx.x, stride = gridDim.x * BLK;
    phase_deg(tid, stride, edges, deg);
    if (!f32) phase_x1_mfma((int)blockIdx.x * 4 + (int)(threadIdx.x >> 6), node_ids, table, sW1T, sB, X);
    else      phase_x1_f32(tid, stride, node_ids, table, W1, sB, X);
}

__global__ __launch_bounds__(BLK, 2)
void k_f2(const int* edges, const unsigned* deg, const float* X, float* acc1) {
    unsigned tid = blockIdx.x * BLK + threadIdx.x, stride = gridDim.x * BLK;
    phase_scatter1(tid, stride, edges, deg, X, acc1);
}

__global__ __launch_bounds__(BLK, 2)
void k_f3(const int* edges, const void* W1, const void* b1, const void* W2, const void* b2,
          const unsigned* deg, const float* acc1, const float* X, float* acc2) {
    __shared__ float sW2[ES * 33];
    __shared__ float sB[2 * ES];
    bool f32 = detect_f32(W1);
    stage_w2b(f32, W2, b1, b2, sW2, sB);
    __syncthreads();
    unsigned tid = blockIdx.x * BLK + threadIdx.x, stride = gridDim.x * BLK;
    phase_x2scatter(tid, stride, edges, deg, acc1, X, sW2, sB, acc2);
}

__global__ __launch_bounds__(BLK, 2)
void k_f4(const void* W1, const void* b1, const void* W2, const void* b2,
          const unsigned* deg, const float* acc1, const float* X, const float* acc2, void* out) {
    __shared__ float sW2[ES * 33];
    __shared__ float sB[2 * ES];
    bool f32 = detect_f32(W1);
    stage_w2b(f32, W2, b1, b2, sW2, sB);
    __syncthreads();
    unsigned tid = blockIdx.x * BLK + threadIdx.x, stride = gridDim.x * BLK;
    phase_out(tid, stride, f32, deg, acc1, X, sW2, sB, acc2, out);
}

extern "C" void kernel_launch(void* const* d_in, const int* in_sizes, int n_in,
                              void* d_out, int out_size, void* d_ws, size_t ws_size,
                              hipStream_t stream) {
    const int* node_ids = (const int*)d_in[0];
    const int* edges    = (const int*)d_in[1];
    const void* table   = d_in[2];
    const void* W1      = d_in[3];
    const void* b1      = d_in[4];
    const void* W2      = d_in[5];
    const void* b2      = d_in[6];

    // ws layout: [deg u32 NN][acc1 f32 NN*ES][acc2 f32 NN*ES][X f32 NN*ES]
    char* ws = (char*)d_ws;
    unsigned* deg = (unsigned*)ws;
    float* acc1   = (float*)(ws + (size_t)NN * 4);
    float* acc2   = acc1 + (size_t)NN * ES;
    float* X      = acc2 + (size_t)NN * ES;
    void* out     = d_out;

    void* args[] = {(void*)&node_ids, (void*)&edges, (void*)&table, (void*)&W1,
                    (void*)&b1, (void*)&W2, (void*)&b2, (void*)&out,
                    (void*)&deg, (void*)&acc1, (void*)&acc2, (void*)&X};
    hipError_t err = hipLaunchCooperativeKernel((const void*)k_mono, dim3(GRID), dim3(BLK),
                                                args, 0u, stream);
    if (err != hipSuccess) {
        (void)hipGetLastError();   // clear; fall back to 5-dispatch pipeline
        hipMemsetAsync(d_ws, 0, (size_t)NN * 4 + 2ull * NN * ES * 4, stream);
        k_f1<<<NN / 64, BLK, 0, stream>>>(node_ids, edges, table, W1, b1, W2, b2, deg, X);
        k_f2<<<(NPC * ES + BLK - 1) / BLK, BLK, 0, stream>>>(edges, deg, X, acc1);
        k_f3<<<(NPC * ES + BLK - 1) / BLK, BLK, 0, stream>>>(edges, W1, b1, W2, b2, deg, acc1, X, acc2);
        k_f4<<<NN * ES / BLK, BLK, 0, stream>>>(W1, b1, W2, b2, deg, acc1, X, acc2, out);
    }
}

// Round 2
// 140.064 us; speedup vs baseline: 2.3780x; 2.3780x over previous
//
#include <hip/hip_runtime.h>
#include <hip/hip_bf16.h>

#define NN 12288
#define ED 256
#define ES 32
#define NPC (NN - 1)      // parent->child edges (edges rows NN..2NN-2)
#define BLK 256
#define W1T_LD 264        // padded leading dim (bf16 elems)

typedef __hip_bfloat16 bf16;
typedef __attribute__((ext_vector_type(8))) short s8v;            // 8 x bf16 (4 VGPR)
typedef __attribute__((ext_vector_type(8))) unsigned short u8v;
typedef __attribute__((ext_vector_type(4))) float f4v;

// ---- dtype detect: f32 tensors reinterpreted as bf16 contain mantissa words
// with random exponents -> huge magnitudes. Deterministic per wave (all waves
// scan the same first 512 bf16-words of W1), so no global flag is needed.
__device__ __forceinline__ bool detect_f32(const void* W1) {
    const unsigned short* p = (const unsigned short*)W1 + (threadIdx.x & 63) * 8;
    u8v v = *(const u8v*)p;
    int huge = 0;
#pragma unroll
    for (int i = 0; i < 8; ++i) {
        unsigned short m = (unsigned short)(v[i] & 0x7fff);
        huge |= (m >= 0x4620);   // |bf16| >= 10240.0
    }
    return __any(huge) != 0;
}

// ---- LDS staging: W2 as f32 [32][33] (conflict-free j-reads), b1|b2 as f32[64]
__device__ __forceinline__ void stage_w2b(bool f32, const void* W2, const void* b1,
                                          const void* b2, float* sW2, float* sB) {
    int t = threadIdx.x;
    for (int i = t; i < ES * ES; i += BLK) {
        float v = f32 ? ((const float*)W2)[i] : __bfloat162float(((const bf16*)W2)[i]);
        sW2[(i >> 5) * 33 + (i & 31)] = v;
    }
    if (t < ES)          sB[t] = f32 ? ((const float*)b1)[t]      : __bfloat162float(((const bf16*)b1)[t]);
    else if (t < 2 * ES) sB[t] = f32 ? ((const float*)b2)[t - ES] : __bfloat162float(((const bf16*)b2)[t - ES]);
}

// ---- W1^T staged in LDS as bf16 [32 cols][W1T_LD k] (bf16 path only).
// thread t owns W1 row t (32 bf16, 4x16B loads), scatters to column-major.
__device__ __forceinline__ void stage_w1t(const void* W1, unsigned short* sW1T) {
    int k = threadIdx.x;
    const u8v* src = (const u8v*)((const unsigned short*)W1 + (size_t)k * ES);
#pragma unroll
    for (int g = 0; g < 4; ++g) {
        u8v v = src[g];
#pragma unroll
        for (int e = 0; e < 8; ++e)
            sW1T[(g * 8 + e) * W1T_LD + k] = v[e];
    }
}

// ---- X1 = emb@W1 + b1 via MFMA (bf16). One 16-node x 32-col tile per wave.
// A row-major [16][K] gathered rows, B^T row-major [32][K] from LDS.
// C/D mapping col=lane&15, row=(lane>>4)*4+i  [HW-verified in prior rounds].
__device__ __forceinline__ void phase_x1_mfma(int gw, const int* node_ids, const void* table,
                                              const unsigned short* sW1T, const float* sB, float* X) {
    if (gw >= NN / 16) return;
    int lane = threadIdx.x & 63;
    int q = lane & 15, hi = lane >> 4;
    int n0 = gw * 16;
    size_t id = (size_t)node_ids[n0 + q];
    const short* ap = (const short*)table + id * ED + hi * 8;
    const unsigned short* bp0 = sW1T + q * W1T_LD + hi * 8;
    const unsigned short* bp1 = sW1T + (q + 16) * W1T_LD + hi * 8;
    f4v a0 = {0.f, 0.f, 0.f, 0.f}, a1 = {0.f, 0.f, 0.f, 0.f};
#pragma unroll
    for (int s = 0; s < ED / 32; ++s) {
        s8v a   = *(const s8v*)(ap + s * 32);
        s8v b0  = *(const s8v*)(bp0 + s * 32);
        s8v b1v = *(const s8v*)(bp1 + s * 32);
        a0 = __builtin_amdgcn_mfma_f32_16x16x32_bf16(a, b0,  a0, 0, 0, 0);
        a1 = __builtin_amdgcn_mfma_f32_16x16x32_bf16(a, b1v, a1, 0, 0, 0);
    }
    float bv0 = sB[q], bv1 = sB[q + 16];
#pragma unroll
    for (int i = 0; i < 4; ++i) {
        int n = n0 + hi * 4 + i;
        X[n * ES + q]      = a0[i] + bv0;
        X[n * ES + q + 16] = a1[i] + bv1;
    }
}

// ---- X1 scalar f32 fallback (correctness path; inputs are bf16 in practice)
__device__ __forceinline__ void phase_x1_f32(unsigned tid, unsigned stride, const int* node_ids,
                                             const void* table, const void* W1,
                                             const float* sB, float* X) {
    for (unsigned t = tid; t < NN * ES; t += stride) {
        int n = t >> 5, j = t & 31;
        const float* e = (const float*)table + (size_t)node_ids[n] * ED;
        const float* w = (const float*)W1;
        float acc = sB[j];
#pragma unroll 8
        for (int k = 0; k < ED; ++k) acc += e[k] * w[k * ES + j];
        X[t] = acc;
    }
}

// =============================== kernels ===============================

// deg (child counts) + X1. Exact grid: 192 blocks x 256 (4 waves -> 4 tiles/block).
__global__ __launch_bounds__(BLK, 2)
void k_f1(const int* __restrict__ node_ids, const int* __restrict__ edges,
          const void* __restrict__ table, const void* __restrict__ W1,
          const void* __restrict__ b1, const void* __restrict__ W2,
          const void* __restrict__ b2, unsigned* __restrict__ deg,
          float* __restrict__ X) {
    __shared__ unsigned short sW1T[ES * W1T_LD];
    __shared__ float sW2[ES * 33];
    __shared__ float sB[2 * ES];
    bool f32 = detect_f32(W1);
    stage_w2b(f32, W2, b1, b2, sW2, sB);
    if (!f32) stage_w1t(W1, sW1T);
    __syncthreads();
    unsigned tid = blockIdx.x * BLK + threadIdx.x, stride = gridDim.x * BLK;
    for (unsigned t = tid; t < NPC; t += stride)
        atomicAdd(&deg[edges[2 * (NN + t)]], 1u);
    if (!f32) phase_x1_mfma((int)blockIdx.x * 4 + (int)(threadIdx.x >> 6), node_ids, table, sW1T, sB, X);
    else      phase_x1_f32(tid, stride, node_ids, table, W1, sB, X);
}

// acc1[r] += w_rc * X1[c] over pc edges only (self-loop folded at use).
__global__ __launch_bounds__(BLK, 2)
void k_f2(const int* __restrict__ edges, const unsigned* __restrict__ deg,
          const float* __restrict__ X, float* __restrict__ acc1) {
    unsigned t = blockIdx.x * BLK + threadIdx.x;
    if (t >= NPC * ES) return;
    int e = t >> 5, k = t & 31;
    int r = edges[2 * (NN + e)], c = edges[2 * (NN + e) + 1];
    float w = rsqrtf((float)deg[r] + 1.f) * rsqrtf((float)deg[c] + 1.f);
    atomicAdd(&acc1[r * ES + k], w * X[c * ES + k]);
}

// Per pc edge: h1[c] = relu(acc1[c] + (1/deg_c) X1[c]); X2[c] via shfl mat-vec
// against LDS W2; scatter w_rc * X2[c] into acc2[r]. Each c occurs exactly once.
__global__ __launch_bounds__(BLK, 2)
void k_f3(const int* __restrict__ edges, const void* __restrict__ W1,
          const void* __restrict__ b1, const void* __restrict__ W2,
          const void* __restrict__ b2, const unsigned* __restrict__ deg,
          const float* __restrict__ acc1, const float* __restrict__ X,
          float* __restrict__ acc2) {
    __shared__ float sW2[ES * 33];
    __shared__ float sB[2 * ES];
    bool f32 = detect_f32(W1);
    stage_w2b(f32, W2, b1, b2, sW2, sB);
    __syncthreads();
    unsigned t = blockIdx.x * BLK + threadIdx.x;
    if (t >= NPC * ES) return;
    int e = t >> 5, j = t & 31;
    int r = edges[2 * (NN + e)], c = edges[2 * (NN + e) + 1];
    float rc = rsqrtf((float)deg[c] + 1.f);
    float h = fmaxf(acc1[c * ES + j] + (rc * rc) * X[c * ES + j], 0.f);
    float x2 = sB[ES + j];
#pragma unroll
    for (int k = 0; k < ES; ++k)
        x2 += __shfl(h, k, ES) * sW2[k * 33 + j];
    float w = rsqrtf((float)deg[r] + 1.f) * rc;
    atomicAdd(&acc2[r * ES + j], w * x2);
}

// out[n] = relu(acc2[n] + (1/deg_n) * X2[n]); X2[n] recomputed via shfl mat-vec.
__global__ __launch_bounds__(BLK, 2)
void k_f4(const void* __restrict__ W1, const void* __restrict__ b1,
          const void* __restrict__ W2, const void* __restrict__ b2,
          const unsigned* __restrict__ deg, const float* __restrict__ acc1,
          const float* __restrict__ X, const float* __restrict__ acc2,
          void* __restrict__ out) {
    __shared__ float sW2[ES * 33];
    __shared__ float sB[2 * ES];
    bool f32 = detect_f32(W1);
    stage_w2b(f32, W2, b1, b2, sW2, sB);
    __syncthreads();
    unsigned t = blockIdx.x * BLK + threadIdx.x;   // exact grid: NN*ES/BLK
    int n = t >> 5, j = t & 31;
    float rn = rsqrtf((float)deg[n] + 1.f);
    float sw = rn * rn;
    float h = fmaxf(acc1[n * ES + j] + sw * X[n * ES + j], 0.f);
    float x2 = sB[ES + j];
#pragma unroll
    for (int k = 0; k < ES; ++k)
        x2 += __shfl(h, k, ES) * sW2[k * 33 + j];
    float v = fmaxf(acc2[n * ES + j] + sw * x2, 0.f);
    if (f32) ((float*)out)[t] = v;
    else     ((bf16*)out)[t]  = __float2bfloat16(v);
}

extern "C" void kernel_launch(void* const* d_in, const int* in_sizes, int n_in,
                              void* d_out, int out_size, void* d_ws, size_t ws_size,
                              hipStream_t stream) {
    const int* node_ids = (const int*)d_in[0];
    const int* edges    = (const int*)d_in[1];
    const void* table   = d_in[2];
    const void* W1      = d_in[3];
    const void* b1      = d_in[4];
    const void* W2      = d_in[5];
    const void* b2      = d_in[6];

    // ws layout: [deg u32 NN][acc1 f32 NN*ES][acc2 f32 NN*ES][X f32 NN*ES]
    char* ws = (char*)d_ws;
    unsigned* deg = (unsigned*)ws;
    float* acc1   = (float*)(ws + (size_t)NN * 4);
    float* acc2   = acc1 + (size_t)NN * ES;
    float* X      = acc2 + (size_t)NN * ES;

    // zero deg + acc1 + acc2 (contiguous prefix, ~3.2 MB)
    hipMemsetAsync(d_ws, 0, (size_t)NN * 4 + 2ull * NN * ES * 4, stream);

    const int g_edge = (NPC * ES + BLK - 1) / BLK;   // 1536 blocks (last partial)
    const int g_node = NN * ES / BLK;                 // 1536 blocks, exact

    k_f1<<<NN / 64, BLK, 0, stream>>>(node_ids, edges, table, W1, b1, W2, b2, deg, X);
    k_f2<<<g_edge, BLK, 0, stream>>>(edges, deg, X, acc1);
    k_f3<<<g_edge, BLK, 0, stream>>>(edges, W1, b1, W2, b2, deg, acc1, X, acc2);
    k_f4<<<g_node, BLK, 0, stream>>>(W1, b1, W2, b2, deg, acc1, X, acc2, d_out);
}

// Round 5
// 107.878 us; speedup vs baseline: 3.0875x; 1.2984x over previous
//
#include <hip/hip_runtime.h>
#include <hip/hip_bf16.h>

#define NN 12288
#define ED 256
#define ES 32
#define NPC (NN - 1)      // parent->child edges: edges rows NN..2NN-2 are (parent[i], i), i=1..NN-1
#define BLK 256

typedef __hip_bfloat16 bf16;
typedef __attribute__((ext_vector_type(8))) unsigned short u8v;

// ---- dtype detect (HW-verified rounds 0-2): f32 tensors reinterpreted as bf16
// contain mantissa words with random exponents -> huge magnitudes. Wave-uniform
// (all lanes scan the same first 1 KB of W1); in_sizes is in ELEMENTS (round-4
// post-mortem) so dtype CANNOT be resolved on the host.
__device__ __forceinline__ bool detect_f32(const void* W1) {
    const unsigned short* p = (const unsigned short*)W1 + (threadIdx.x & 63) * 8;
    u8v v = *(const u8v*)p;
    int huge = 0;
#pragma unroll
    for (int i = 0; i < 8; ++i) {
        unsigned short m = (unsigned short)(v[i] & 0x7fff);
        huge |= (m >= 0x4620);   // |bf16| >= 10240.0
    }
    return __any(huge) != 0;
}

__device__ __forceinline__ float ldv(const void* p, int i, bool f32) {
    return f32 ? ((const float*)p)[i] : __bfloat162float(((const bf16*)p)[i]);
}

// ---- k1: deg histogram (child counts; consumers use deg+1) + X1 = emb@W1 + b1.
// One output element per thread, 1536 blocks: latency hidden by TLP (~24 waves/CU).
// Per fixed k: e[k] is a wave-broadcast load, w[k*ES+j] is coalesced -> L1/L2-hot.
__global__ __launch_bounds__(BLK)
void k1(const int* __restrict__ node_ids, const int* __restrict__ edges,
        const void* __restrict__ table, const void* __restrict__ W1,
        const void* __restrict__ b1, unsigned* __restrict__ deg,
        float* __restrict__ X) {
    bool f32 = detect_f32(W1);
    unsigned t = blockIdx.x * BLK + threadIdx.x;      // exact grid: NN*ES threads
    if (t < NPC) atomicAdd(&deg[edges[2 * (NN + t)]], 1u);
    int n = t >> 5, j = t & 31;
    size_t id = (size_t)node_ids[n];
    float acc = ldv(b1, j, f32);
    if (f32) {
        const float* e = (const float*)table + id * ED;
        const float* w = (const float*)W1;
        #pragma unroll 8
        for (int k = 0; k < ED; ++k) acc += e[k] * w[k * ES + j];
    } else {
        const bf16* e = (const bf16*)table + id * ED;
        const bf16* w = (const bf16*)W1;
        #pragma unroll 8
        for (int k = 0; k < ED; ++k)
            acc += __bfloat162float(e[k]) * __bfloat162float(w[k * ES + j]);
    }
    X[t] = acc;
}

// ---- k2: acc1[r] += w_rc * X1[c] per pc edge (self-loop folded at use).
// c = e+1 by construction -> X/deg[c] reads coalesced; only r is indirect.
__global__ __launch_bounds__(BLK)
void k2(const int* __restrict__ edges, const unsigned* __restrict__ deg,
        const float* __restrict__ X, float* __restrict__ acc1) {
    unsigned t = blockIdx.x * BLK + threadIdx.x;
    if (t >= (unsigned)NPC * ES) return;
    int e = t >> 5, k = t & 31;
    int c = e + 1;
    int r = edges[2 * (NN + e)];                      // parent (wave-broadcast load)
    float w = rsqrtf((float)deg[r] + 1.f) * rsqrtf((float)deg[c] + 1.f);
    atomicAdd(&acc1[r * ES + k], w * X[c * ES + k]);
}

// ---- k3: per pc edge, h1[c] = relu(acc1[c] + (1/deg_c) X1[c]); X2[c] via
// shfl mat-vec against LDS W2; scatter w_rc * X2[c] into acc2[r].
// Each c occurs exactly once, so X2 is computed once per node here.
__global__ __launch_bounds__(BLK)
void k3(const int* __restrict__ edges, const void* __restrict__ W1,
        const void* __restrict__ W2, const void* __restrict__ b2,
        const unsigned* __restrict__ deg, const float* __restrict__ acc1,
        const float* __restrict__ X, float* __restrict__ acc2) {
    __shared__ float sW2[ES * 33];                    // [k][j], padded: conflict-free j-reads
    __shared__ float sB[ES];
    bool f32 = detect_f32(W1);
    int tt = threadIdx.x;
    for (int i = tt; i < ES * ES; i += BLK) sW2[(i >> 5) * 33 + (i & 31)] = ldv(W2, i, f32);
    if (tt < ES) sB[tt] = ldv(b2, tt, f32);
    __syncthreads();
    unsigned t = blockIdx.x * BLK + tt;
    if (t >= (unsigned)NPC * ES) return;
    int e = t >> 5, j = t & 31;
    int c = e + 1;
    int r = edges[2 * (NN + e)];
    float rc = rsqrtf((float)deg[c] + 1.f);
    float h = fmaxf(acc1[c * ES + j] + (rc * rc) * X[c * ES + j], 0.f);
    float x2 = sB[j];
    #pragma unroll
    for (int k = 0; k < ES; ++k)
        x2 += __shfl(h, k, ES) * sW2[k * 33 + j];
    float w = rsqrtf((float)deg[r] + 1.f) * rc;
    atomicAdd(&acc2[r * ES + j], w * x2);
}

// ---- k4: out[n] = relu(acc2[n] + (1/deg_n) * X2[n]); X2[n] recomputed
// (all loads coalesced; X2 recompute is 32 shfl-FMAs, trivial VALU).
// Output dtype follows input dtype (f32 path passed rounds 0-2).
__global__ __launch_bounds__(BLK)
void k4(const void* __restrict__ W1, const void* __restrict__ W2,
        const void* __restrict__ b2, const unsigned* __restrict__ deg,
        const float* __restrict__ acc1, const float* __restrict__ X,
        const float* __restrict__ acc2, void* __restrict__ out) {
    __shared__ float sW2[ES * 33];
    __shared__ float sB[ES];
    bool f32 = detect_f32(W1);
    int tt = threadIdx.x;
    for (int i = tt; i < ES * ES; i += BLK) sW2[(i >> 5) * 33 + (i & 31)] = ldv(W2, i, f32);
    if (tt < ES) sB[tt] = ldv(b2, tt, f32);
    __syncthreads();
    unsigned t = blockIdx.x * BLK + tt;               // exact grid: NN*ES threads
    int n = t >> 5, j = t & 31;
    float rn = rsqrtf((float)deg[n] + 1.f);
    float sw = rn * rn;
    float h = fmaxf(acc1[n * ES + j] + sw * X[n * ES + j], 0.f);
    float x2 = sB[j];
    #pragma unroll
    for (int k = 0; k < ES; ++k)
        x2 += __shfl(h, k, ES) * sW2[k * 33 + j];
    float v = fmaxf(acc2[n * ES + j] + sw * x2, 0.f);
    if (f32) ((float*)out)[t] = v;
    else     ((bf16*)out)[t]  = __float2bfloat16(v);
}

extern "C" void kernel_launch(void* const* d_in, const int* in_sizes, int n_in,
                              void* d_out, int out_size, void* d_ws, size_t ws_size,
                              hipStream_t stream) {
    const int* node_ids = (const int*)d_in[0];
    const int* edges    = (const int*)d_in[1];
    const void* table   = d_in[2];
    const void* W1      = d_in[3];
    const void* b1      = d_in[4];
    const void* W2      = d_in[5];
    const void* b2      = d_in[6];

    // ws layout: [deg u32 NN][acc1 f32 NN*ES][acc2 f32 NN*ES][X f32 NN*ES]
    char* ws = (char*)d_ws;
    unsigned* deg = (unsigned*)ws;
    float* acc1   = (float*)(ws + (size_t)NN * 4);
    float* acc2   = acc1 + (size_t)NN * ES;
    float* X      = acc2 + (size_t)NN * ES;

    // zero deg + acc1 + acc2 (contiguous prefix, ~3.2 MB)
    hipMemsetAsync(d_ws, 0, (size_t)NN * 4 + 2ull * NN * ES * 4, stream);

    const int g_node = NN * ES / BLK;                 // 1536, exact
    const int g_edge = (NPC * ES + BLK - 1) / BLK;    // 1536, last block partial

    k1<<<g_node, BLK, 0, stream>>>(node_ids, edges, table, W1, b1, deg, X);
    k2<<<g_edge, BLK, 0, stream>>>(edges, deg, X, acc1);
    k3<<<g_edge, BLK, 0, stream>>>(edges, W1, W2, b2, deg, acc1, X, acc2);
    k4<<<g_node, BLK, 0, stream>>>(W1, W2, b2, deg, acc1, X, acc2, d_out);
}

// Round 6
// 88.300 us; speedup vs baseline: 3.7720x; 1.2217x over previous
//
#include <hip/hip_runtime.h>
#include <hip/hip_bf16.h>

#define NN 12288
#define ED 256
#define ES 32
#define NPC (NN - 1)      // parent->child edges: edges rows NN..2NN-2 are (parent[i], i), i=1..NN-1
#define BLK 256

typedef __hip_bfloat16 bf16;
typedef __attribute__((ext_vector_type(8))) short s8v;            // 8 x bf16 (4 VGPR)
typedef __attribute__((ext_vector_type(8))) unsigned short u8v;
typedef __attribute__((ext_vector_type(4))) float f4v;

// ---- dtype detect (HW-verified rounds 0-2,5): f32 tensors reinterpreted as
// bf16 contain mantissa words with random exponents -> huge magnitudes.
// Wave-uniform; in_sizes is in ELEMENTS so dtype cannot be resolved on host.
__device__ __forceinline__ bool detect_f32(const void* W1) {
    const unsigned short* p = (const unsigned short*)W1 + (threadIdx.x & 63) * 8;
    u8v v = *(const u8v*)p;
    int huge = 0;
#pragma unroll
    for (int i = 0; i < 8; ++i) {
        unsigned short m = (unsigned short)(v[i] & 0x7fff);
        huge |= (m >= 0x4620);   // |bf16| >= 10240.0
    }
    return __any(huge) != 0;
}

__device__ __forceinline__ float ldv(const void* p, int i, bool f32) {
    return f32 ? ((const float*)p)[i] : __bfloat162float(((const bf16*)p)[i]);
}

__device__ __forceinline__ unsigned short f2bf(float f) {   // RNE f32->bf16 bits
    bf16 h = __float2bfloat16(f);
    return __builtin_bit_cast(unsigned short, h);
}

// ---- k1: deg histogram + X1 = emb@W1 + b1 via bf16 MFMA (f32 accum).
// Block = 64 nodes (4 waves x 16). W1^T staged in LDS as bf16 [32 j][256 k],
// 16B-block XOR swizzle (blk ^= j&7): fragment reads land 2 lanes/bank (free).
// A-fragments gathered from global per lane (row = node's table row), with
// in-register f32->bf16 RNE cvt when inputs are f32.
__global__ __launch_bounds__(BLK)
void k1(const int* __restrict__ node_ids, const int* __restrict__ edges,
        const void* __restrict__ table, const void* __restrict__ W1,
        const void* __restrict__ b1, unsigned* __restrict__ deg,
        float* __restrict__ X) {
    __shared__ unsigned short sW1T[ES * ED];          // 16 KB
    bool f32 = detect_f32(W1);
    int tt = threadIdx.x;
    unsigned t = blockIdx.x * BLK + tt;               // grid 192*256 = 49152 >= NPC
    if (t < NPC) atomicAdd(&deg[edges[2 * (NN + t)]], 1u);

    // stage W1^T (bf16, swizzled): thread (j = tt&31, kc = tt>>5) does 4 blocks
    {
        int j = tt & 31, kc = tt >> 5;
        for (int it = 0; it < 4; ++it) {
            int kb = kc + 8 * it;                     // 16B block = 8 k values
            u8v v;
            if (f32) {
                const float* w = (const float*)W1;
#pragma unroll
                for (int e = 0; e < 8; ++e) v[e] = f2bf(w[(kb * 8 + e) * ES + j]);
            } else {
                const unsigned short* w = (const unsigned short*)W1;
#pragma unroll
                for (int e = 0; e < 8; ++e) v[e] = w[(kb * 8 + e) * ES + j];
            }
            *(u8v*)&sW1T[j * ED + ((kb ^ (j & 7)) * 8)] = v;
        }
    }
    __syncthreads();

    // MFMA: wave computes 16 nodes x 32 cols. A row q = node n0+q, k-offset hi*8.
    int lane = tt & 63;
    int q = lane & 15, hi = lane >> 4;
    int n0 = blockIdx.x * 64 + (tt >> 6) * 16;
    size_t id = (size_t)node_ids[n0 + q];
    f4v a0 = {0.f, 0.f, 0.f, 0.f}, a1 = {0.f, 0.f, 0.f, 0.f};
    int sw = q & 7;
    if (f32) {
        const float* e = (const float*)table + id * ED + hi * 8;
#pragma unroll
        for (int s = 0; s < 8; ++s) {
            f4v e0 = *(const f4v*)(e + s * 32);
            f4v e1 = *(const f4v*)(e + s * 32 + 4);
            u8v av;
#pragma unroll
            for (int i = 0; i < 4; ++i) { av[i] = f2bf(e0[i]); av[4 + i] = f2bf(e1[i]); }
            int blk = (hi + 4 * s) ^ sw;
            s8v b0  = *(const s8v*)&sW1T[q * ED + blk * 8];
            s8v b1v = *(const s8v*)&sW1T[(q + 16) * ED + blk * 8];
            s8v a = __builtin_bit_cast(s8v, av);
            a0 = __builtin_amdgcn_mfma_f32_16x16x32_bf16(a, b0,  a0, 0, 0, 0);
            a1 = __builtin_amdgcn_mfma_f32_16x16x32_bf16(a, b1v, a1, 0, 0, 0);
        }
    } else {
        const short* e = (const short*)table + id * ED + hi * 8;
#pragma unroll
        for (int s = 0; s < 8; ++s) {
            s8v a = *(const s8v*)(e + s * 32);
            int blk = (hi + 4 * s) ^ sw;
            s8v b0  = *(const s8v*)&sW1T[q * ED + blk * 8];
            s8v b1v = *(const s8v*)&sW1T[(q + 16) * ED + blk * 8];
            a0 = __builtin_amdgcn_mfma_f32_16x16x32_bf16(a, b0,  a0, 0, 0, 0);
            a1 = __builtin_amdgcn_mfma_f32_16x16x32_bf16(a, b1v, a1, 0, 0, 0);
        }
    }
    // C/D mapping: col = lane&15, row = (lane>>4)*4 + i  [m89/m91-verified]
    float bv0 = ldv(b1, q, f32), bv1 = ldv(b1, q + 16, f32);
#pragma unroll
    for (int i = 0; i < 4; ++i) {
        int n = n0 + hi * 4 + i;
        X[n * ES + q]      = a0[i] + bv0;
        X[n * ES + q + 16] = a1[i] + bv1;
    }
}

// ---- k2: acc1[r] += w_rc * X1[c] per pc edge (self-loop folded at use).
// c = e+1 by construction -> X/deg[c] reads coalesced; only r is indirect.
__global__ __launch_bounds__(BLK)
void k2(const int* __restrict__ edges, const unsigned* __restrict__ deg,
        const float* __restrict__ X, float* __restrict__ acc1) {
    unsigned t = blockIdx.x * BLK + threadIdx.x;
    if (t >= (unsigned)NPC * ES) return;
    int e = t >> 5, k = t & 31;
    int c = e + 1;
    int r = edges[2 * (NN + e)];                      // parent (wave-broadcast load)
    float w = rsqrtf((float)deg[r] + 1.f) * rsqrtf((float)deg[c] + 1.f);
    atomicAdd(&acc1[r * ES + k], w * X[c * ES + k]);
}

// ---- k3: per pc edge, h1[c] = relu(acc1[c] + (1/deg_c) X1[c]); X2[c] via
// shfl mat-vec against LDS W2; scatter w_rc * X2[c] into acc2[r].
__global__ __launch_bounds__(BLK)
void k3(const int* __restrict__ edges, const void* __restrict__ W1,
        const void* __restrict__ W2, const void* __restrict__ b2,
        const unsigned* __restrict__ deg, const float* __restrict__ acc1,
        const float* __restrict__ X, float* __restrict__ acc2) {
    __shared__ float sW2[ES * 33];                    // [k][j], padded: conflict-free j-reads
    __shared__ float sB[ES];
    bool f32 = detect_f32(W1);
    int tt = threadIdx.x;
    for (int i = tt; i < ES * ES; i += BLK) sW2[(i >> 5) * 33 + (i & 31)] = ldv(W2, i, f32);
    if (tt < ES) sB[tt] = ldv(b2, tt, f32);
    __syncthreads();
    unsigned t = blockIdx.x * BLK + tt;
    if (t >= (unsigned)NPC * ES) return;
    int e = t >> 5, j = t & 31;
    int c = e + 1;
    int r = edges[2 * (NN + e)];
    float rc = rsqrtf((float)deg[c] + 1.f);
    float h = fmaxf(acc1[c * ES + j] + (rc * rc) * X[c * ES + j], 0.f);
    float x2 = sB[j];
    #pragma unroll
    for (int k = 0; k < ES; ++k)
        x2 += __shfl(h, k, ES) * sW2[k * 33 + j];
    float w = rsqrtf((float)deg[r] + 1.f) * rc;
    atomicAdd(&acc2[r * ES + j], w * x2);
}

// ---- k4: out[n] = relu(acc2[n] + (1/deg_n) * X2[n]); X2[n] recomputed.
// Output dtype follows input dtype (f32 path passed rounds 0-2,5).
__global__ __launch_bounds__(BLK)
void k4(const void* __restrict__ W1, const void* __restrict__ W2,
        const void* __restrict__ b2, const unsigned* __restrict__ deg,
        const float* __restrict__ acc1, const float* __restrict__ X,
        const float* __restrict__ acc2, void* __restrict__ out) {
    __shared__ float sW2[ES * 33];
    __shared__ float sB[ES];
    bool f32 = detect_f32(W1);
    int tt = threadIdx.x;
    for (int i = tt; i < ES * ES; i += BLK) sW2[(i >> 5) * 33 + (i & 31)] = ldv(W2, i, f32);
    if (tt < ES) sB[tt] = ldv(b2, tt, f32);
    __syncthreads();
    unsigned t = blockIdx.x * BLK + tt;               // exact grid: NN*ES threads
    int n = t >> 5, j = t & 31;
    float rn = rsqrtf((float)deg[n] + 1.f);
    float sw = rn * rn;
    float h = fmaxf(acc1[n * ES + j] + sw * X[n * ES + j], 0.f);
    float x2 = sB[j];
    #pragma unroll
    for (int k = 0; k < ES; ++k)
        x2 += __shfl(h, k, ES) * sW2[k * 33 + j];
    float v = fmaxf(acc2[n * ES + j] + sw * x2, 0.f);
    if (f32) ((float*)out)[t] = v;
    else     ((bf16*)out)[t]  = __float2bfloat16(v);
}

extern "C" void kernel_launch(void* const* d_in, const int* in_sizes, int n_in,
                              void* d_out, int out_size, void* d_ws, size_t ws_size,
                              hipStream_t stream) {
    const int* node_ids = (const int*)d_in[0];
    const int* edges    = (const int*)d_in[1];
    const void* table   = d_in[2];
    const void* W1      = d_in[3];
    const void* b1      = d_in[4];
    const void* W2      = d_in[5];
    const void* b2      = d_in[6];

    // ws layout: [deg u32 NN][acc1 f32 NN*ES][acc2 f32 NN*ES][X f32 NN*ES]
    char* ws = (char*)d_ws;
    unsigned* deg = (unsigned*)ws;
    float* acc1   = (float*)(ws + (size_t)NN * 4);
    float* acc2   = acc1 + (size_t)NN * ES;
    float* X      = acc2 + (size_t)NN * ES;

    // zero deg + acc1 + acc2 (contiguous prefix, ~3.2 MB)
    hipMemsetAsync(d_ws, 0, (size_t)NN * 4 + 2ull * NN * ES * 4, stream);

    const int g_mfma = NN / 64;                       // 192 blocks, 64 nodes each
    const int g_node = NN * ES / BLK;                 // 1536, exact
    const int g_edge = (NPC * ES + BLK - 1) / BLK;    // 1536, last block partial

    k1<<<g_mfma, BLK, 0, stream>>>(node_ids, edges, table, W1, b1, deg, X);
    k2<<<g_edge, BLK, 0, stream>>>(edges, deg, X, acc1);
    k3<<<g_edge, BLK, 0, stream>>>(edges, W1, W2, b2, deg, acc1, X, acc2);
    k4<<<g_node, BLK, 0, stream>>>(W1, W2, b2, deg, acc1, X, acc2, d_out);
}